// Round 4
// baseline (406.979 us; speedup 1.0000x reference)
//
#include <hip/hip_runtime.h>
#include <hip/hip_bf16.h>

#define N_ANCH 100800
#define BATCH 64
#define KTOP 512
#define CNT_STRIDE 64   // pad counters to 256 B so each lives on its own L2 line

// ---------------------------------------------------------------------------
// K0: zero the per-image candidate counters (ws is poisoned 0xAA each call)
// ---------------------------------------------------------------------------
__global__ void zero_cnt_kernel(int* __restrict__ cnt) {
    if (threadIdx.x < BATCH) cnt[threadIdx.x * CNT_STRIDE] = 0;
}

// ---------------------------------------------------------------------------
// K1: filter — score = p4*p5 > 0.7, compact (score_bits<<32 | ~idx) keys into
// per-image candidate lists. Direct strided loads (every 64B line of pred is
// touched anyway since rows are 36B; L1 absorbs within-wave line reuse), so
// no LDS staging. 1024 rows/block -> 4x fewer blocks/barriers than R3.
// grid = (ceil(N/1024), B), block = 1024.
// ---------------------------------------------------------------------------
__global__ void __launch_bounds__(1024)
filter_kernel(const float* __restrict__ pred,
              unsigned long long* __restrict__ cand,
              int* __restrict__ cnt, int cap) {
#pragma clang fp contract(off)
    __shared__ int s_wbase[16];
    __shared__ int s_blkcnt;
    __shared__ int s_gbase;

    const int b = blockIdx.y;
    const int t = threadIdx.x;
    const int r = blockIdx.x * 1024 + t;
    const int wid = t >> 6, lane = t & 63;

    if (t == 0) s_blkcnt = 0;
    __syncthreads();

    bool has = false;
    unsigned long long key = 0;
    if (r < N_ANCH) {
        const float* row = pred + ((size_t)b * N_ANCH + r) * 9;
        float s = row[4] * row[5];
        if (s > 0.7f) {
            has = true;
            unsigned int sb = __float_as_uint(s);
            unsigned int gi = (unsigned int)r;
            key = ((unsigned long long)sb << 32) | (unsigned long long)(~gi);
        }
    }

    unsigned long long m = __ballot(has);
    if (lane == 0) s_wbase[wid] = atomicAdd(&s_blkcnt, __popcll(m));
    __syncthreads();
    if (t == 0) s_gbase = atomicAdd(&cnt[b * CNT_STRIDE], s_blkcnt);
    __syncthreads();

    if (has) {
        int rank = __popcll(m & ((1ull << lane) - 1ull));
        int pos = s_gbase + s_wbase[wid] + rank;
        if (pos < cap) cand[(size_t)b * cap + pos] = key;
    }
}

// ---------------------------------------------------------------------------
// K2: per-image top-512 select + sort + IoU bitmask + greedy + output.
// grid = B, block = 1024. Barrier-minimized: wave-level suffix scan for the
// bucket cut, hybrid shfl/LDS bitonic (45 barrier-free shuffle phases + 10
// LDS phases), register-buffered candidate keys (one global pass).
// ---------------------------------------------------------------------------
__global__ void __launch_bounds__(1024)
nms_kernel(const float* __restrict__ pred,
           const unsigned long long* __restrict__ cand,
           const int* __restrict__ cnt,
           float* __restrict__ out, int cap) {
#pragma clang fp contract(off)
    __shared__ int hist[2048];
    __shared__ unsigned long long sel[1024];
    __shared__ float4 boxes[KTOP];
    __shared__ unsigned long long msk[KTOP][8];
    __shared__ unsigned long long rmw[8];
    __shared__ int s_bstar, s_nsel;

    const int b = blockIdx.x;
    const int t = threadIdx.x;
    const int c = min(cnt[b * CNT_STRIDE], cap);
    const unsigned long long* __restrict__ cb = cand + (size_t)b * cap;

    for (int i = t; i < 2048; i += 1024) hist[i] = 0;
    sel[t] = 0;
    if (t == 0) { s_nsel = 0; s_bstar = 0; }
    __syncthreads();

    // --- one global pass: buffer keys in registers + LDS histogram ---------
    unsigned long long kreg[8];
    int nk = 0;
    for (int i = t; i < c; i += 1024) {
        unsigned long long k = cb[i];
        kreg[nk++] = k;
        atomicAdd(&hist[(int)((k >> 44) & 0x7FF)], 1);
    }
    __syncthreads();

    // --- wave 0: suffix-scan the 2048-bucket histogram to find cut bstar ---
    if (t < 64) {
        const int4* h4 = (const int4*)hist;
        int S = 0;
        #pragma unroll
        for (int mch = 0; mch < 8; ++mch) {
            int4 v = h4[(t << 3) + mch];
            S += v.x + v.y + v.z + v.w;
        }
        // suffix sums across 64 lanes
        #pragma unroll
        for (int off = 1; off < 64; off <<= 1) {
            int v2 = __shfl_down(S, off);
            if (t + off < 64) S += v2;
        }
        unsigned long long m1 = __ballot(S >= KTOP);
        int bstar = 0;
        if (m1) {
            int lstar = 63 - __clzll(m1);                 // crossing 32-bucket chunk
            int nxt = __shfl(S, (lstar + 1) & 63);
            int carry = (lstar < 63) ? nxt : 0;
            int C = (t < 32) ? hist[(lstar << 5) + t] : 0;
            #pragma unroll
            for (int off = 1; off < 32; off <<= 1) {
                int v2 = __shfl_down(C, off);
                if (t + off < 32) C += v2;
            }
            C += carry;
            unsigned long long m2 = __ballot((t < 32) && (C >= KTOP));
            int jstar = 63 - __clzll(m2);
            bstar = (lstar << 5) + jstar;                 // max k with suffix(k) >= 512
        }
        if (t == 0) s_bstar = bstar;
    }
    __syncthreads();

    // --- compact candidates in buckets >= bstar (~520 expected) ------------
    const int bstar = s_bstar;
    #pragma unroll
    for (int u = 0; u < 8; ++u) {
        if (u < nk) {
            unsigned long long k = kreg[u];
            if ((int)((k >> 44) & 0x7FF) >= bstar) {
                int p = atomicAdd(&s_nsel, 1);
                if (p < 1024) sel[p] = k;
            }
        }
    }
    __syncthreads();
    const int v = min(s_nsel, KTOP);

    // --- hybrid bitonic sort, 1024 keys descending, keys in registers ------
    {
        unsigned long long key = sel[t];
        for (int k = 2; k <= 1024; k <<= 1) {
            for (int j = k >> 1; j > 0; j >>= 1) {
                unsigned long long other;
                if (j >= 64) {                  // cross-wave: LDS exchange
                    sel[t] = key;
                    __syncthreads();
                    other = sel[t ^ j];
                    __syncthreads();
                } else {                        // in-wave: shuffle, no barrier
                    other = __shfl_xor(key, j, 64);
                }
                bool descSeg = ((t & k) == 0);
                bool lower   = ((t & j) == 0);
                bool keepMax = (descSeg == lower);
                bool takeOther = keepMax ? (other > key) : (other < key);
                if (takeOther) key = other;
            }
        }
        sel[t] = key;
        __syncthreads();
    }

    // --- gather top-512 rows, xywh -> xyxy ----------------------------------
    if (t < KTOP) {
        float4 bx = make_float4(0.f, 0.f, 0.f, 0.f);
        if (t < v) {
            unsigned long long k = sel[t];
            int gid = (int)(~(unsigned int)(k & 0xFFFFFFFFull));
            const float* row = pred + ((size_t)b * N_ANCH + gid) * 9;
            float cx = row[0], cy = row[1], w = row[2], h = row[3];
            float hw = w * 0.5f, hh = h * 0.5f;   // exact halving
            bx = make_float4(cx - hw, cy - hh, cx + hw, cy + hh);
        }
        boxes[t] = bx;
    }
    __syncthreads();

    // --- IoU bitmask: thread owns row pair (2q, 2q+1) x 2 strips; bj read
    // once per strip, used for both rows (halves LDS b128 traffic) ----------
    {
        const int q  = t & 255;
        const int i0 = q << 1, i1 = i0 + 1;
        const int wp = t >> 8;                    // 0..3 -> strips 2wp, 2wp+1
        float4 b0 = boxes[i0], b1 = boxes[i1];
        float a0 = (b0.z - b0.x) * (b0.w - b0.y);
        float a1 = (b1.z - b1.x) * (b1.w - b1.y);
        #pragma unroll
        for (int s = 0; s < 2; ++s) {
            const int w = (wp << 1) + s;
            const int j0 = w << 6;
            unsigned long long m0 = 0, m1 = 0;
            if (j0 + 63 > i0) {                   // strip has some j > i0 (=> maybe i1)
                #pragma unroll 8
                for (int jj = 0; jj < 64; ++jj) {
                    float4 bj = boxes[j0 + jj];
                    float aj = (bj.z - bj.x) * (bj.w - bj.y);
                    {
                        float xx1 = fmaxf(b0.x, bj.x);
                        float yy1 = fmaxf(b0.y, bj.y);
                        float xx2 = fminf(b0.z, bj.z);
                        float yy2 = fminf(b0.w, bj.w);
                        float ww = fmaxf(xx2 - xx1, 0.f);
                        float hh = fmaxf(yy2 - yy1, 0.f);
                        float inter = ww * hh;
                        float uni = a0 + aj - inter;
                        float iou = inter / (uni + 1e-7f);
                        m0 |= (unsigned long long)(iou > 0.45f) << jj;
                    }
                    {
                        float xx1 = fmaxf(b1.x, bj.x);
                        float yy1 = fmaxf(b1.y, bj.y);
                        float xx2 = fminf(b1.z, bj.z);
                        float yy2 = fminf(b1.w, bj.w);
                        float ww = fmaxf(xx2 - xx1, 0.f);
                        float hh = fmaxf(yy2 - yy1, 0.f);
                        float inter = ww * hh;
                        float uni = a1 + aj - inter;
                        float iou = inter / (uni + 1e-7f);
                        m1 |= (unsigned long long)(iou > 0.45f) << jj;
                    }
                }
                if (j0 <= i0) {
                    int sh = i0 - j0 + 1;
                    m0 = (sh >= 64) ? 0ull : (m0 & ((~0ull) << sh));
                }
                if (j0 <= i1) {
                    int sh = i1 - j0 + 1;
                    m1 = (sh >= 64) ? 0ull : (m1 & ((~0ull) << sh));
                }
            }
            msk[i0][w] = m0;
            msk[i1][w] = m1;
        }
    }
    __syncthreads();

    // --- greedy suppression: visit only kept boxes via ffs over alive mask --
    if (t == 0) {
        unsigned long long rm[8] = {0, 0, 0, 0, 0, 0, 0, 0};
        for (int w = 0; w < 8 && (w << 6) < v; ++w) {
            int rem = v - (w << 6);
            unsigned long long valid = (rem >= 64) ? ~0ull : ((1ull << rem) - 1ull);
            unsigned long long alive = ~rm[w] & valid;
            while (alive) {
                int bit = __ffsll(alive) - 1;
                int i = (w << 6) + bit;
                #pragma unroll
                for (int u = 0; u < 8; ++u) rm[u] |= msk[i][u];
                alive &= ~rm[w];
                alive &= (bit == 63) ? 0ull : (~0ull << (bit + 1));
            }
        }
        #pragma unroll
        for (int u = 0; u < 8; ++u) rmw[u] = rm[u];
    }
    __syncthreads();

    // --- output: [x1,y1,x2,y2,conf,0,pitch,yaw,roll] or zeros ---------------
    if (t < KTOP) {
        unsigned long long k = sel[t];
        float scv = __uint_as_float((unsigned int)(k >> 32));
        float* o = out + ((size_t)b * KTOP + t) * 9;
        bool keep = (scv > 0.7f) && !((rmw[t >> 6] >> (t & 63)) & 1ull);
        if (keep) {
            int gid = (int)(~(unsigned int)(k & 0xFFFFFFFFull));
            float4 bx = boxes[t];
            const float* row = pred + ((size_t)b * N_ANCH + gid) * 9;
            o[0] = bx.x; o[1] = bx.y; o[2] = bx.z; o[3] = bx.w;
            o[4] = scv; o[5] = 0.f;
            o[6] = row[6]; o[7] = row[7]; o[8] = row[8];
        } else {
            o[0] = 0.f; o[1] = 0.f; o[2] = 0.f; o[3] = 0.f;
            o[4] = 0.f; o[5] = 0.f; o[6] = 0.f; o[7] = 0.f; o[8] = 0.f;
        }
    }
}

// ---------------------------------------------------------------------------
extern "C" void kernel_launch(void* const* d_in, const int* in_sizes, int n_in,
                              void* d_out, int out_size, void* d_ws, size_t ws_size,
                              hipStream_t stream) {
    const float* pred = (const float*)d_in[0];
    float* out = (float*)d_out;

    int* cnt = (int*)d_ws;                                   // 64 counters, 256B stride
    unsigned long long* cand = (unsigned long long*)((char*)d_ws + BATCH * CNT_STRIDE * 4);

    int cap = 8192;   // mean candidates/image ~5073, sigma ~69 -> huge headroom
    size_t head = (size_t)BATCH * CNT_STRIDE * 4;
    size_t need = head + (size_t)BATCH * cap * sizeof(unsigned long long);
    if (ws_size < need) {
        cap = (int)((ws_size > head ? (ws_size - head) : 0) /
                    (BATCH * sizeof(unsigned long long)));
    }

    zero_cnt_kernel<<<1, 64, 0, stream>>>(cnt);

    dim3 g1((N_ANCH + 1023) / 1024, BATCH);
    filter_kernel<<<g1, 1024, 0, stream>>>(pred, cand, cnt, cap);

    nms_kernel<<<BATCH, 1024, 0, stream>>>(pred, cand, cnt, out, cap);
}